// Round 6
// baseline (349.156 us; speedup 1.0000x reference)
//
#include <hip/hip_runtime.h>
#include <hip/hip_bf16.h>

#define B_ 4
#define N_ 8192
#define M_ 2048
#define K_ 8

typedef __bf16 bf16x8 __attribute__((ext_vector_type(8)));
typedef __bf16 bf16x4 __attribute__((ext_vector_type(4)));
typedef float  floatx4 __attribute__((ext_vector_type(4)));
typedef unsigned long long u64k;

// ---------------------------------------------------------------------------
// PRE_KNN (fused, independent work packed in one launch):
//   blocks [0,512)     : KNN, 64 points/block, FULL 2048 candidates
//                        (batch-8 sorting networks on packed u64 keys,
//                        verified R2-R5; no half-split, no merge kernel,
//                        writes final idx[] directly)
//   blocks [512,2560)  : feature2 [B,256,M] fp32 -> f2t [B,M,256] bf16
//   blocks [2560,3408) : weight casts (w1_0 padded 259->288)
// knn blocks go FIRST so the long-pole VALU work starts immediately and the
// memory-bound transpose fills remaining issue slots (pipe overlap on-CU).
// Shared memory is a union: knn needs 32KB P + 16.9KB md = 49664 B.
// ---------------------------------------------------------------------------
__device__ __forceinline__ void ce(u64k& a, u64k& b) {
  u64k lo = a < b ? a : b;
  u64k hi = a < b ? b : a;
  a = lo; b = hi;
}

__global__ __launch_bounds__(256) void pre_knn(
    const float* __restrict__ w10, const float* __restrict__ w11,
    const float* __restrict__ w12, const float* __restrict__ w20,
    const float* __restrict__ feature2,
    const float* __restrict__ pos1, const float* __restrict__ pos2,
    __bf16* __restrict__ w0p, __bf16* __restrict__ w11b,
    __bf16* __restrict__ w12b, __bf16* __restrict__ w20b,
    __bf16* __restrict__ f2t, int* __restrict__ idx_out)
{
  __shared__ __align__(16) char smem[49664];
  const int bid = blockIdx.x;
  const int tid = threadIdx.x;

  if (bid < 512) {
    // ---------------- KNN ----------------
    floatx4* P = (floatx4*)smem;                     // 2048 x 16B = 32 KB
    u64k (*md)[33] = (u64k(*)[33])(smem + 32768);    // 16.9 KB
    const int b = bid >> 7;
    const int n0 = (bid & 127) * 64;

    const float* p2 = pos2 + b * 3 * M_;
    for (int i = tid; i < M_; i += 256) {
      float x = p2[i], y = p2[M_ + i], z = p2[2 * M_ + i];
      floatx4 q;
      q[0] = x; q[1] = y; q[2] = z;
      q[3] = __fadd_rn(__fadd_rn(__fmul_rn(x, x), __fmul_rn(y, y)), __fmul_rn(z, z));
      P[i] = q;
    }
    __syncthreads();

    const int p = tid >> 2, t = tid & 3;
    const int n = n0 + p;
    const float* p1 = pos1 + b * 3 * N_;
    const float x1 = p1[n], y1 = p1[N_ + n], z1 = p1[2 * N_ + n];
    const float r1 = __fadd_rn(__fadd_rn(__fmul_rn(x1, x1), __fmul_rn(y1, y1)),
                               __fmul_rn(z1, z1));

    u64k bd[8];
    #pragma unroll
    for (int r = 0; r < 8; r++) bd[r] = ~0ULL;   // sentinel > any real key

    for (int bb = 0; bb < 64; ++bb) {
      // interleaved stream: candidate c = 4*(8*bb+i)+t (index-ascending/thread)
      floatx4 q[8];
      #pragma unroll
      for (int i = 0; i < 8; i++) q[i] = P[4 * (8 * bb + i) + t];

      u64k s[8];
      #pragma unroll
      for (int i = 0; i < 8; i++) {
        float dot = __fadd_rn(__fadd_rn(__fmul_rn(x1, q[i][0]), __fmul_rn(y1, q[i][1])),
                              __fmul_rn(z1, q[i][2]));
        float d = __fsub_rn(__fadd_rn(r1, q[i][3]), __fmul_rn(2.0f, dot));
        unsigned du = __float_as_uint(d);
        unsigned k32 = du ^ ((unsigned)((int)du >> 31) | 0x80000000u);  // monotone
        s[i] = ((u64k)k32 << 11) | (unsigned)(4 * (8 * bb + i) + t);
      }

      // Batcher odd-even mergesort, 8 elements, 19 comparators
      ce(s[0], s[1]); ce(s[2], s[3]); ce(s[4], s[5]); ce(s[6], s[7]);
      ce(s[0], s[2]); ce(s[1], s[3]); ce(s[4], s[6]); ce(s[5], s[7]);
      ce(s[1], s[2]); ce(s[5], s[6]);
      ce(s[0], s[4]); ce(s[1], s[5]); ce(s[2], s[6]); ce(s[3], s[7]);
      ce(s[2], s[4]); ce(s[3], s[5]);
      ce(s[1], s[2]); ce(s[3], s[4]); ce(s[5], s[6]);

      if (s[0] < bd[7]) {
        // bitonic low-8 of merge(bd asc, s asc)
        #pragma unroll
        for (int k = 0; k < 8; k++) { u64k x = s[7 - k]; bd[k] = bd[k] < x ? bd[k] : x; }
        ce(bd[0], bd[4]); ce(bd[1], bd[5]); ce(bd[2], bd[6]); ce(bd[3], bd[7]);
        ce(bd[0], bd[2]); ce(bd[1], bd[3]); ce(bd[4], bd[6]); ce(bd[5], bd[7]);
        ce(bd[0], bd[1]); ce(bd[2], bd[3]); ce(bd[4], bd[5]); ce(bd[6], bd[7]);
      }
    }

    #pragma unroll
    for (int r = 0; r < 8; r++) md[p][t * 8 + r] = bd[r];
    __syncthreads();

    // 4-way lexicographic merge of the sorted lists == lax.top_k order
    if (tid < 64) {
      int h0 = 0, h1 = 0, h2 = 0, h3 = 0;
      int* o = idx_out + ((size_t)(b * N_ + n0 + tid)) * 8;
      #pragma unroll
      for (int r = 0; r < 8; r++) {
        u64k k0 = md[tid][h0], k1 = md[tid][8 + h1];
        u64k k2 = md[tid][16 + h2], k3 = md[tid][24 + h3];
        u64k m01 = k0 < k1 ? k0 : k1;
        u64k m23 = k2 < k3 ? k2 : k3;
        u64k m = m01 < m23 ? m01 : m23;
        h0 += (k0 == m); h1 += (k1 == m); h2 += (k2 == m); h3 += (k3 == m);
        o[r] = (int)(m & 2047u);
      }
    }
  } else if (bid < 2560) {
    // ---------------- feature2 transpose+cast ----------------
    float (*tile)[33] = (float(*)[33])smem;
    const int tb = bid - 512;
    const int C = 256, L = M_;
    const int b = tb >> 9;
    const int c0 = ((tb >> 6) & 7) * 32, l0 = (tb & 63) * 32;
    const int tx = tid & 31, ty = tid >> 5;   // ty 0..7
    const float* src = feature2 + (size_t)b * C * L;
    #pragma unroll
    for (int i = 0; i < 4; i++)
      tile[ty + 8 * i][tx] = src[(size_t)(c0 + ty + 8 * i) * L + l0 + tx];
    __syncthreads();
    __bf16* dst = f2t + (size_t)b * L * C;
    #pragma unroll
    for (int i = 0; i < 4; i++)
      dst[(size_t)(l0 + ty + 8 * i) * C + c0 + tx] = (__bf16)tile[tx][ty + 8 * i];
  } else {
    // ---------------- weight casts ----------------
    int t = (bid - 2560) * 256 + tid;
    if (t < 36864) {
      int o = t / 288, c = t - o * 288;
      w0p[t] = (c < 259) ? (__bf16)w10[o * 259 + c] : (__bf16)0.0f;
    } else if (t < 53248) {
      int i = t - 36864; w11b[i] = (__bf16)w11[i];
    } else if (t < 86016) {
      int i = t - 53248; w12b[i] = (__bf16)w12[i];
    } else if (t < 217088) {
      int i = t - 86016; w20b[i] = (__bf16)w20[i];
    }
  }
}

// ---------------------------------------------------------------------------
// Swizzled-X MFMA k-loop (no epilogue): X is a 64-row x 128-col bf16 LDS tile
// with 256B rows and chunk-XOR swizzle (byte_chunk ^= (row&7)<<4). Weights
// global (L2-hot), next-kstep register prefetch. Fills acc[4][2].
// Fragment maps (gfx950, HW-verified): A[m=lane&15][k=quad*8+j] = W row
// (out-col) c0+m; B[n=lane&15][k] = X row pt*16+n;
// D: lane(lrow,quad) reg r holds [out-col c0+quad*4+r][point-row pt*16+lrow].
// ---------------------------------------------------------------------------
template <int KSTEPS>
__device__ __forceinline__ void mfma_kloop_swz(
    const __bf16* X, const __bf16* W, int wstride, int c0, int lane,
    floatx4 (&acc)[4][2])
{
  const int lrow = lane & 15, quad = lane >> 4;
  const floatx4 fz = {0.f, 0.f, 0.f, 0.f};
  #pragma unroll
  for (int pt = 0; pt < 4; pt++) { acc[pt][0] = fz; acc[pt][1] = fz; }

  bf16x8 wf0 = *(const bf16x8*)(W + (size_t)(c0 + lrow) * wstride + quad * 8);
  bf16x8 wf1 = *(const bf16x8*)(W + (size_t)(c0 + 16 + lrow) * wstride + quad * 8);
  bf16x8 xf[4];
  #pragma unroll
  for (int pt = 0; pt < 4; pt++) {
    const int row = pt * 16 + lrow;
    xf[pt] = *(const bf16x8*)((const char*)X + row * 256
                              + ((quad * 16) ^ ((row & 7) << 4)));
  }

  #pragma unroll
  for (int ks = 0; ks < KSTEPS; ks++) {
    bf16x8 wn0, wn1, xn[4];
    if (ks + 1 < KSTEPS) {
      const int kn = (ks + 1) * 32 + quad * 8;
      wn0 = *(const bf16x8*)(W + (size_t)(c0 + lrow) * wstride + kn);
      wn1 = *(const bf16x8*)(W + (size_t)(c0 + 16 + lrow) * wstride + kn);
      #pragma unroll
      for (int pt = 0; pt < 4; pt++) {
        const int row = pt * 16 + lrow;
        xn[pt] = *(const bf16x8*)((const char*)X + row * 256
                                  + (((ks + 1) * 64 + quad * 16) ^ ((row & 7) << 4)));
      }
    }
    #pragma unroll
    for (int pt = 0; pt < 4; pt++) {
      acc[pt][0] = __builtin_amdgcn_mfma_f32_16x16x32_bf16(wf0, xf[pt], acc[pt][0], 0, 0, 0);
      acc[pt][1] = __builtin_amdgcn_mfma_f32_16x16x32_bf16(wf1, xf[pt], acc[pt][1], 0, 0, 0);
    }
    if (ks + 1 < KSTEPS) {
      wf0 = wn0; wf1 = wn1;
      #pragma unroll
      for (int pt = 0; pt < 4; pt++) xf[pt] = xn[pt];
    }
  }
}

// ---------------------------------------------------------------------------
// MLP1 (v5-exact, measured 104.9us in R4; R5's fused-merge prologue reverted).
// LDS = Xs[64*256] = 32768 B exactly. Y1 aliases lower 16KB (dead after L0
// k-loop); Y0 aliases upper 16KB (freed by bar2); Mst aliases upper after L1.
// In-register maxpool via shfl_xor; full 512B/point coalesced stores.
// Barriers: (1) post-DMA (2) post-L0-kloop (3) Y0 ready (4) Y1 ready
// (5) Mst ready.
// ---------------------------------------------------------------------------
__global__ __launch_bounds__(256, 4) void mlp1_kernel(
    const float* __restrict__ pos1, const float* __restrict__ pos2,
    const int* __restrict__ idx, const __bf16* __restrict__ f2t,
    const __bf16* __restrict__ w0p, const float* __restrict__ s10, const float* __restrict__ b10,
    const __bf16* __restrict__ w11b, const float* __restrict__ s11, const float* __restrict__ b11,
    const __bf16* __restrict__ w12b, const float* __restrict__ s12, const float* __restrict__ b12,
    __bf16* __restrict__ maxed)
{
  __shared__ __align__(16) __bf16 Xs[64 * 256];   // 32768 B exactly
  __bf16* const Y1 = Xs;                          // lower 16KB (post-L0)
  __bf16* const Y0 = Xs + 32 * 256;               // upper 16KB (post-bar2)
  __bf16* const Mst = Xs + 32 * 256;              // 8 x 264 bf16 (post-bar4)

  const int b = blockIdx.y;
  const int n0 = blockIdx.x * 8;
  const int tid = threadIdx.x;
  const int wave = tid >> 6, lane = tid & 63;
  const int lrow = lane & 15, quad = lane >> 4;
  const int c0 = 32 * wave;
  const int idxbase = (b * N_ + n0) * K_;

  // ---- stage DMA: wave w stages rows [16w,16w+16) (2 rows per instr:
  // lanes 0-31 -> row r, lanes 32-63 -> row r+1; 1KB linear dest).
  // Source 16B chunk XORed by (row&7) so swizzled L0 reads are conflict-free.
  {
    const int r0 = wave * 16;
    const int hf = lane >> 5;
    const int ch = lane & 31;
    int mr[8];
    #pragma unroll
    for (int i = 0; i < 8; i++)
      mr[i] = idx[idxbase + r0 + 2 * i + hf];     // broadcast within half-wave
    #pragma unroll
    for (int i = 0; i < 8; i++) {
      const int r = r0 + 2 * i + hf;
      const char* src = (const char*)f2t
          + (((size_t)(b * M_ + mr[i])) << 9)
          + ((ch << 4) ^ ((r & 7) << 4));
      __builtin_amdgcn_global_load_lds(
          (const __attribute__((address_space(1))) unsigned int*)src,
          (__attribute__((address_space(3))) unsigned int*)(Xs + (r0 + 2 * i) * 256),
          16, 0, 0);
    }
  }

  // ---- posdiff last-k fragment (quad 0 lanes only) while DMA in flight
  bf16x8 xlast[4];
  #pragma unroll
  for (int pt = 0; pt < 4; pt++) { bf16x8 v = {}; xlast[pt] = v; }
  if (quad == 0) {
    #pragma unroll
    for (int pt = 0; pt < 4; pt++) {
      const int r = pt * 16 + lrow;
      const int m = idx[idxbase + r];
      const int n = n0 + (r >> 3);
      bf16x8 v = {};
      v[0] = (__bf16)(pos2[b * 3 * M_ + m]          - pos1[b * 3 * N_ + n]);
      v[1] = (__bf16)(pos2[b * 3 * M_ + M_ + m]     - pos1[b * 3 * N_ + N_ + n]);
      v[2] = (__bf16)(pos2[b * 3 * M_ + 2 * M_ + m] - pos1[b * 3 * N_ + 2 * N_ + n]);
      xlast[pt] = v;
    }
  }

  // W k-step-0 fragments issued before the barrier
  bf16x8 wf0 = *(const bf16x8*)(w0p + (size_t)(c0 + lrow) * 288 + quad * 8);
  bf16x8 wf1 = *(const bf16x8*)(w0p + (size_t)(c0 + 16 + lrow) * 288 + quad * 8);

  __syncthreads();                 // (1) all DMAs complete

  // ---- L0: K=288 = 8 LDS ksteps + posdiff step. Acc in registers.
  floatx4 acc[4][2];
  {
    const floatx4 fz = {0.f, 0.f, 0.f, 0.f};
    #pragma unroll
    for (int pt = 0; pt < 4; pt++) { acc[pt][0] = fz; acc[pt][1] = fz; }

    const int swz = (lrow & 7) << 4;     // byte XOR within a 512B Xs row
    bf16x8 xf[4];
    #pragma unroll
    for (int pt = 0; pt < 4; pt++)
      xf[pt] = *(const bf16x8*)((const char*)Xs + (pt * 16 + lrow) * 512
                                + ((quad * 16) ^ swz));

    #pragma unroll
    for (int ks = 0; ks < 9; ks++) {
      bf16x8 wn0, wn1, xn[4];
      if (ks < 8) {
        const int kn = (ks + 1) * 32 + quad * 8;
        wn0 = *(const bf16x8*)(w0p + (size_t)(c0 + lrow) * 288 + kn);
        wn1 = *(const bf16x8*)(w0p + (size_t)(c0 + 16 + lrow) * 288 + kn);
        if (ks < 7) {
          const int kb = ((ks + 1) * 64 + quad * 16) ^ swz;
          #pragma unroll
          for (int pt = 0; pt < 4; pt++)
            xn[pt] = *(const bf16x8*)((const char*)Xs + (pt * 16 + lrow) * 512 + kb);
        } else {
          #pragma unroll
          for (int pt = 0; pt < 4; pt++) xn[pt] = xlast[pt];
        }
      }
      #pragma unroll
      for (int pt = 0; pt < 4; pt++) {
        acc[pt][0] = __builtin_amdgcn_mfma_f32_16x16x32_bf16(wf0, xf[pt], acc[pt][0], 0, 0, 0);
        acc[pt][1] = __builtin_amdgcn_mfma_f32_16x16x32_bf16(wf1, xf[pt], acc[pt][1], 0, 0, 0);
      }
      if (ks < 8) {
        wf0 = wn0; wf1 = wn1;
        #pragma unroll
        for (int pt = 0; pt < 4; pt++) xf[pt] = xn[pt];
      }
    }
  }

  __syncthreads();                 // (2) all waves past Xs reads -> upper free

  // ---- L0 epilogue -> Y0 (upper 16KB), swizzled
  #pragma unroll
  for (int pt = 0; pt < 4; pt++) {
    #pragma unroll
    for (int wt = 0; wt < 2; wt++) {
      const int colg = c0 + wt * 16 + quad * 4;
      floatx4 s4 = *(const floatx4*)(s10 + colg);
      floatx4 b4 = *(const floatx4*)(b10 + colg);
      bf16x4 pk;
      #pragma unroll
      for (int r = 0; r < 4; r++) {
        float v = acc[pt][wt][r] * s4[r] + b4[r];
        pk[r] = (__bf16)(v > 0.f ? v : 0.f);
      }
      const int row = pt * 16 + lrow;
      const int cb = colg * 2;
      *(bf16x4*)((char*)Y0 + row * 256
                 + ((cb & ~15) ^ ((row & 7) << 4)) + (cb & 15)) = pk;
    }
  }
  __syncthreads();                 // (3) Y0 ready

  // ---- L1: 128 -> 128, Y0 -> Y1 (lower 16KB)
  {
    floatx4 a1c[4][2];
    mfma_kloop_swz<4>(Y0, w11b, 128, c0, lane, a1c);
    #pragma unroll
    for (int pt = 0; pt < 4; pt++) {
      #pragma unroll
      for (int wt = 0; wt < 2; wt++) {
        const int colg = c0 + wt * 16 + quad * 4;
        floatx4 s4 = *(const floatx4*)(s11 + colg);
        floatx4 b4 = *(const floatx4*)(b11 + colg);
        bf16x4 pk;
        #pragma unroll
        for (int r = 0; r < 4; r++) {
          float v = a1c[pt][wt][r] * s4[r] + b4[r];
          pk[r] = (__bf16)(v > 0.f ? v : 0.f);
        }
        const int row = pt * 16 + lrow;
        const int cb = colg * 2;
        *(bf16x4*)((char*)Y1 + row * 256
                   + ((cb & ~15) ^ ((row & 7) << 4)) + (cb & 15)) = pk;
      }
    }
  }
  __syncthreads();                 // (4) Y1 ready; upper region -> Mst

  // ---- L2: two 128-col passes, acc in regs, IN-REGISTER maxpool.
  // Lane's 4 acc values = 4 out-cols of rank-row pt*16+lrow; the 8 ranks of
  // point pt*2+(lrow>>3) live across lanes (lrow&7) -> shfl_xor 1,2,4 max.
  #pragma unroll
  for (int p = 0; p < 2; p++) {
    floatx4 a2c[4][2];
    mfma_kloop_swz<4>(Y1, w12b, 128, 128 * p + c0, lane, a2c);
    #pragma unroll
    for (int pt = 0; pt < 4; pt++) {
      #pragma unroll
      for (int wt = 0; wt < 2; wt++) {
        const int colg = 128 * p + c0 + wt * 16 + quad * 4;
        floatx4 s4 = *(const floatx4*)(s12 + colg);
        floatx4 b4 = *(const floatx4*)(b12 + colg);
        floatx4 v;
        #pragma unroll
        for (int r = 0; r < 4; r++) {
          float t = a2c[pt][wt][r] * s4[r] + b4[r];
          v[r] = t > 0.f ? t : 0.f;
        }
        #pragma unroll
        for (int st = 1; st <= 4; st <<= 1) {
          #pragma unroll
          for (int r = 0; r < 4; r++)
            v[r] = fmaxf(v[r], __shfl_xor(v[r], st, 64));
        }
        if ((lrow & 7) == 0) {
          const int point = pt * 2 + (lrow >> 3);
          bf16x4 pk;
          #pragma unroll
          for (int r = 0; r < 4; r++) pk[r] = (__bf16)v[r];
          *(bf16x4*)(Mst + point * 264 + colg) = pk;
        }
      }
    }
  }
  __syncthreads();                 // (5) Mst complete

  // ---- store: full 512B per point row, 32 consecutive lanes (full lines)
  {
    const int point = tid >> 5, ch = tid & 31;
    bf16x8 v = *(const bf16x8*)(Mst + point * 264 + ch * 8);
    *(bf16x8*)(maxed + ((size_t)(b * N_ + n0 + point)) * 256 + ch * 8) = v;
  }
}

// ---------------------------------------------------------------------------
// MLP2: 32 rows x 128 out-cols per block, grid (1024, 2) = 2048 blocks.
// k>=256 A-fragments read feature1 [B,256,N] fp32 directly (64B segments per
// quad) with inline (__bf16) RNE cast -- measured ~= bf16 path + 2us while
// saving the 32MB f1t round-trip (R4->R5 accounting). Out fp32 floatx4.
// ---------------------------------------------------------------------------
__global__ __launch_bounds__(256, 4) void mlp2_kernel(
    const __bf16* __restrict__ maxed, const float* __restrict__ feature1,
    const __bf16* __restrict__ w20b, const float* __restrict__ s20,
    const float* __restrict__ b20, float* __restrict__ out)
{
  const int rows0 = blockIdx.x * 32;           // b*N + n
  const int b = rows0 >> 13;
  const int nbase = rows0 & (N_ - 1);
  const int tid = threadIdx.x;
  const int wave = tid >> 6, lane = tid & 63;
  const int lrow = lane & 15, quad = lane >> 4;
  const int c0 = 128 * blockIdx.y + 32 * wave;
  const floatx4 fz = {0.f, 0.f, 0.f, 0.f};

  floatx4 acc[2][2];
  acc[0][0] = fz; acc[0][1] = fz; acc[1][0] = fz; acc[1][1] = fz;

  auto afrag = [&](int ks, int mt) -> bf16x8 {
    const int k = ks * 32 + quad * 8;
    if (ks < 8) {
      return *(const bf16x8*)(maxed + (size_t)(rows0 + mt * 16 + lrow) * 256 + k);
    } else {
      const int c = k - 256;
      const float* p = feature1 + ((size_t)(b * 256 + c)) * N_
                       + (nbase + mt * 16 + lrow);
      bf16x8 v;
      #pragma unroll
      for (int j = 0; j < 8; j++) v[j] = (__bf16)p[(size_t)j * N_];
      return v;
    }
  };

  bf16x8 w0 = *(const bf16x8*)(w20b + (size_t)(c0 + lrow) * 512 + quad * 8);
  bf16x8 w1 = *(const bf16x8*)(w20b + (size_t)(c0 + 16 + lrow) * 512 + quad * 8);
  bf16x8 a0 = afrag(0, 0);
  bf16x8 a1 = afrag(0, 1);

  #pragma unroll
  for (int ks = 0; ks < 16; ks++) {
    bf16x8 wn0, wn1, an0, an1;
    if (ks < 15) {
      const int kn = (ks + 1) * 32 + quad * 8;
      wn0 = *(const bf16x8*)(w20b + (size_t)(c0 + lrow) * 512 + kn);
      wn1 = *(const bf16x8*)(w20b + (size_t)(c0 + 16 + lrow) * 512 + kn);
      an0 = afrag(ks + 1, 0);
      an1 = afrag(ks + 1, 1);
    }
    acc[0][0] = __builtin_amdgcn_mfma_f32_16x16x32_bf16(a0, w0, acc[0][0], 0, 0, 0);
    acc[0][1] = __builtin_amdgcn_mfma_f32_16x16x32_bf16(a0, w1, acc[0][1], 0, 0, 0);
    acc[1][0] = __builtin_amdgcn_mfma_f32_16x16x32_bf16(a1, w0, acc[1][0], 0, 0, 0);
    acc[1][1] = __builtin_amdgcn_mfma_f32_16x16x32_bf16(a1, w1, acc[1][1], 0, 0, 0);
    if (ks < 15) { w0 = wn0; w1 = wn1; a0 = an0; a1 = an1; }
  }

  #pragma unroll
  for (int ct = 0; ct < 2; ct++) {
    const int col = c0 + ct * 16 + lrow;
    const float s = s20[col];
    const float bb = b20[col];
    #pragma unroll
    for (int mt = 0; mt < 2; mt++) {
      floatx4 pk;
      #pragma unroll
      for (int r = 0; r < 4; r++) {
        float v = acc[mt][ct][r] * s + bb;
        pk[r] = v > 0.f ? v : 0.f;
      }
      const int n = nbase + mt * 16 + quad * 4;
      *(floatx4*)(out + ((size_t)(b * 256 + col)) * N_ + n) = pk;
    }
  }
}

// ---------------------------------------------------------------------------
extern "C" void kernel_launch(void* const* d_in, const int* in_sizes, int n_in,
                              void* d_out, int out_size, void* d_ws, size_t ws_size,
                              hipStream_t stream)
{
  const float* pos1     = (const float*)d_in[0];
  const float* pos2     = (const float*)d_in[1];
  const float* feature1 = (const float*)d_in[2];
  const float* feature2 = (const float*)d_in[3];
  const float* w1_0 = (const float*)d_in[4];
  const float* s1_0 = (const float*)d_in[5];
  const float* b1_0 = (const float*)d_in[6];
  const float* w1_1 = (const float*)d_in[7];
  const float* s1_1 = (const float*)d_in[8];
  const float* b1_1 = (const float*)d_in[9];
  const float* w1_2 = (const float*)d_in[10];
  const float* s1_2 = (const float*)d_in[11];
  const float* b1_2 = (const float*)d_in[12];
  const float* w2_0 = (const float*)d_in[13];
  const float* s2_0 = (const float*)d_in[14];
  const float* b2_0 = (const float*)d_in[15];

  // Workspace layout
  char* ws = (char*)d_ws;
  int*    idx   = (int*)(ws);                    //  1,048,576 @ 0
  __bf16* f2t   = (__bf16*)(ws + 1048576);       //  4,194,304
  __bf16* maxed = (__bf16*)(ws + 22020096);      // 16,777,216
  __bf16* w0p   = (__bf16*)(ws + 38797312);      //     73,728
  __bf16* w11b  = (__bf16*)(ws + 38871040);      //     32,768
  __bf16* w12b  = (__bf16*)(ws + 38903808);      //     65,536
  __bf16* w20b  = (__bf16*)(ws + 38969344);      //    262,144

  pre_knn<<<dim3(3408), 256, 0, stream>>>(
      w1_0, w1_1, w1_2, w2_0, feature2, pos1, pos2,
      w0p, w11b, w12b, w20b, f2t, idx);
  mlp1_kernel<<<dim3(N_ / 8, B_), 256, 0, stream>>>(
      pos1, pos2, idx, f2t, w0p, s1_0, b1_0, w11b, s1_1, b1_1, w12b, s1_2, b1_2, maxed);
  mlp2_kernel<<<dim3(1024, 2), 256, 0, stream>>>(maxed, feature1, w20b, s2_0, b2_0,
                                                 (float*)d_out);
}

// Round 7
// 306.039 us; speedup vs baseline: 1.1409x; 1.1409x over previous
//
#include <hip/hip_runtime.h>
#include <hip/hip_bf16.h>

#define B_ 4
#define N_ 8192
#define M_ 2048
#define K_ 8

typedef __bf16 bf16x8 __attribute__((ext_vector_type(8)));
typedef __bf16 bf16x4 __attribute__((ext_vector_type(4)));
typedef float  floatx4 __attribute__((ext_vector_type(4)));
typedef unsigned long long u64k;

#define AS1G __attribute__((address_space(1)))
#define AS3L __attribute__((address_space(3)))

// ---------------------------------------------------------------------------
// PRE_KNN (fused independent work):
//   blocks [0,1024)      : KNN split-2 (verified R2-R5 structure), 64 pts &
//                          1024 candidates per block -> part[] sorted-8 keys
//   blocks [1024,3072)   : feature2 [B,256,M]   fp32 -> f2t bf16 transpose
//   blocks [3072,11264)  : feature1 [B,256,N]   fp32 -> f1t bf16 transpose
//   blocks [11264,12112) : weight casts (w1_0 padded 259->288)
// knn LDS trimmed to EXACTLY 32768 B (md unpadded [64][32] + free XOR column
// swizzle replaces the +1 pad) -> 5 blocks/CU (was 4) for the VALU-bound scan.
// ---------------------------------------------------------------------------
__device__ __forceinline__ void ce(u64k& a, u64k& b) {
  u64k lo = a < b ? a : b;
  u64k hi = a < b ? b : a;
  a = lo; b = hi;
}

__global__ __launch_bounds__(256) void pre_knn(
    const float* __restrict__ w10, const float* __restrict__ w11,
    const float* __restrict__ w12, const float* __restrict__ w20,
    const float* __restrict__ feature1, const float* __restrict__ feature2,
    const float* __restrict__ pos1, const float* __restrict__ pos2,
    __bf16* __restrict__ w0p, __bf16* __restrict__ w11b,
    __bf16* __restrict__ w12b, __bf16* __restrict__ w20b,
    __bf16* __restrict__ f2t, __bf16* __restrict__ f1t,
    u64k* __restrict__ part)
{
  __shared__ __align__(16) char smem[32768];
  const int bid = blockIdx.x;
  const int tid = threadIdx.x;

  if (bid < 1024) {
    // ---------------- KNN (split-2) ----------------
    floatx4* P = (floatx4*)smem;                     // 1024 x 16B = 16 KB
    u64k (*md)[32] = (u64k(*)[32])(smem + 16384);    // 16 KB (unpadded)
    const int b = (bid >> 7) & 3;
    const int half = bid >> 9;
    const int n0 = (bid & 127) * 64;
    const int cbase = half * 1024;

    const float* p2 = pos2 + b * 3 * M_;
    for (int i = tid; i < 1024; i += 256) {
      const int c = cbase + i;
      float x = p2[c], y = p2[M_ + c], z = p2[2 * M_ + c];
      floatx4 q;
      q[0] = x; q[1] = y; q[2] = z;
      q[3] = __fadd_rn(__fadd_rn(__fmul_rn(x, x), __fmul_rn(y, y)), __fmul_rn(z, z));
      P[i] = q;
    }
    __syncthreads();

    const int p = tid >> 2, t = tid & 3;
    const int n = n0 + p;
    const float* p1 = pos1 + b * 3 * N_;
    const float x1 = p1[n], y1 = p1[N_ + n], z1 = p1[2 * N_ + n];
    const float r1 = __fadd_rn(__fadd_rn(__fmul_rn(x1, x1), __fmul_rn(y1, y1)),
                               __fmul_rn(z1, z1));

    u64k bd[8];
    #pragma unroll
    for (int r = 0; r < 8; r++) bd[r] = ~0ULL;   // sentinel > any real key

    for (int bb = 0; bb < 32; ++bb) {
      floatx4 q[8];
      #pragma unroll
      for (int i = 0; i < 8; i++) q[i] = P[4 * (8 * bb + i) + t];

      u64k s[8];
      #pragma unroll
      for (int i = 0; i < 8; i++) {
        float dot = __fadd_rn(__fadd_rn(__fmul_rn(x1, q[i][0]), __fmul_rn(y1, q[i][1])),
                              __fmul_rn(z1, q[i][2]));
        float d = __fsub_rn(__fadd_rn(r1, q[i][3]), __fmul_rn(2.0f, dot));
        unsigned du = __float_as_uint(d);
        unsigned k32 = du ^ ((unsigned)((int)du >> 31) | 0x80000000u);  // monotone
        s[i] = ((u64k)k32 << 11) | (unsigned)(cbase + 4 * (8 * bb + i) + t);
      }

      // Batcher odd-even mergesort, 8 elements, 19 comparators
      ce(s[0], s[1]); ce(s[2], s[3]); ce(s[4], s[5]); ce(s[6], s[7]);
      ce(s[0], s[2]); ce(s[1], s[3]); ce(s[4], s[6]); ce(s[5], s[7]);
      ce(s[1], s[2]); ce(s[5], s[6]);
      ce(s[0], s[4]); ce(s[1], s[5]); ce(s[2], s[6]); ce(s[3], s[7]);
      ce(s[2], s[4]); ce(s[3], s[5]);
      ce(s[1], s[2]); ce(s[3], s[4]); ce(s[5], s[6]);

      if (s[0] < bd[7]) {
        // bitonic low-8 of merge(bd asc, s asc)
        #pragma unroll
        for (int k = 0; k < 8; k++) { u64k x = s[7 - k]; bd[k] = bd[k] < x ? bd[k] : x; }
        ce(bd[0], bd[4]); ce(bd[1], bd[5]); ce(bd[2], bd[6]); ce(bd[3], bd[7]);
        ce(bd[0], bd[2]); ce(bd[1], bd[3]); ce(bd[4], bd[6]); ce(bd[5], bd[7]);
        ce(bd[0], bd[1]); ce(bd[2], bd[3]); ce(bd[4], bd[5]); ce(bd[6], bd[7]);
      }
    }

    // column XOR-swizzle (t-field only) replaces the +1 row pad for banks
    {
      const int swp = (p & 3) << 3;
      #pragma unroll
      for (int r = 0; r < 8; r++) md[p][(t * 8 + r) ^ swp] = bd[r];
    }
    __syncthreads();

    // 4-way lexicographic merge of the sorted lists == lax.top_k order
    if (tid < 64) {
      const int sw = tid & 3;
      const int b0 = (0 ^ sw) << 3, b1 = (1 ^ sw) << 3;
      const int b2 = (2 ^ sw) << 3, b3 = (3 ^ sw) << 3;
      int h0 = 0, h1 = 0, h2 = 0, h3 = 0;
      u64k* o = part + ((size_t)((b * 2 + half) * N_ + n0 + tid)) * 8;
      #pragma unroll
      for (int r = 0; r < 8; r++) {
        u64k k0 = md[tid][b0 + h0], k1 = md[tid][b1 + h1];
        u64k k2 = md[tid][b2 + h2], k3 = md[tid][b3 + h3];
        u64k m01 = k0 < k1 ? k0 : k1;
        u64k m23 = k2 < k3 ? k2 : k3;
        u64k m = m01 < m23 ? m01 : m23;
        h0 += (k0 == m); h1 += (k1 == m); h2 += (k2 == m); h3 += (k3 == m);
        o[r] = m;
      }
    }
  } else if (bid < 3072) {
    // ---------------- feature2 transpose+cast (L = M_) ----------------
    float (*tile)[33] = (float(*)[33])smem;
    const int tb = bid - 1024;
    const int C = 256, L = M_;
    const int b = tb >> 9;
    const int c0 = ((tb >> 6) & 7) * 32, l0 = (tb & 63) * 32;
    const int tx = tid & 31, ty = tid >> 5;
    const float* src = feature2 + (size_t)b * C * L;
    #pragma unroll
    for (int i = 0; i < 4; i++)
      tile[ty + 8 * i][tx] = src[(size_t)(c0 + ty + 8 * i) * L + l0 + tx];
    __syncthreads();
    __bf16* dst = f2t + (size_t)b * L * C;
    #pragma unroll
    for (int i = 0; i < 4; i++)
      dst[(size_t)(l0 + ty + 8 * i) * C + c0 + tx] = (__bf16)tile[tx][ty + 8 * i];
  } else if (bid < 11264) {
    // ---------------- feature1 transpose+cast (L = N_) ----------------
    float (*tile)[33] = (float(*)[33])smem;
    const int tb = bid - 3072;
    const int C = 256, L = N_;
    const int b = tb >> 11;
    const int c0 = ((tb >> 8) & 7) * 32, l0 = (tb & 255) * 32;
    const int tx = tid & 31, ty = tid >> 5;
    const float* src = feature1 + (size_t)b * C * L;
    #pragma unroll
    for (int i = 0; i < 4; i++)
      tile[ty + 8 * i][tx] = src[(size_t)(c0 + ty + 8 * i) * L + l0 + tx];
    __syncthreads();
    __bf16* dst = f1t + (size_t)b * L * C;
    #pragma unroll
    for (int i = 0; i < 4; i++)
      dst[(size_t)(l0 + ty + 8 * i) * C + c0 + tx] = (__bf16)tile[tx][ty + 8 * i];
  } else {
    // ---------------- weight casts ----------------
    int t = (bid - 11264) * 256 + tid;
    if (t < 36864) {
      int o = t / 288, c = t - o * 288;
      w0p[t] = (c < 259) ? (__bf16)w10[o * 259 + c] : (__bf16)0.0f;
    } else if (t < 53248) {
      int i = t - 36864; w11b[i] = (__bf16)w11[i];
    } else if (t < 86016) {
      int i = t - 53248; w12b[i] = (__bf16)w12[i];
    } else if (t < 217088) {
      int i = t - 86016; w20b[i] = (__bf16)w20[i];
    }
  }
}

// ---------------------------------------------------------------------------
// Merge the two candidate-half sorted-8 key lists -> final neighbor indices.
// (verified R2-R4)
// ---------------------------------------------------------------------------
__global__ __launch_bounds__(256) void knn_merge(
    const u64k* __restrict__ part, int* __restrict__ idx_out)
{
  const int pt = blockIdx.x * 256 + threadIdx.x;     // 0..32767
  const int b = pt >> 13, n = pt & (N_ - 1);
  const u64k* a0 = part + ((size_t)((b * 2 + 0) * N_ + n)) * 8;
  const u64k* a1 = part + ((size_t)((b * 2 + 1) * N_ + n)) * 8;
  u64k av[8], cv[8];
  #pragma unroll
  for (int r = 0; r < 8; r++) { av[r] = a0[r]; cv[r] = a1[r]; }
  #pragma unroll
  for (int k = 0; k < 8; k++) { u64k x = cv[7 - k]; av[k] = av[k] < x ? av[k] : x; }
  ce(av[0], av[4]); ce(av[1], av[5]); ce(av[2], av[6]); ce(av[3], av[7]);
  ce(av[0], av[2]); ce(av[1], av[3]); ce(av[4], av[6]); ce(av[5], av[7]);
  ce(av[0], av[1]); ce(av[2], av[3]); ce(av[4], av[5]); ce(av[6], av[7]);
  int* o = idx_out + (size_t)pt * 8;
  #pragma unroll
  for (int r = 0; r < 8; r++) o[r] = (int)(av[r] & 2047u);
}

// ---------------------------------------------------------------------------
// Swizzled-X MFMA k-loop (no epilogue) -- verified mlp1 component.
// ---------------------------------------------------------------------------
template <int KSTEPS>
__device__ __forceinline__ void mfma_kloop_swz(
    const __bf16* X, const __bf16* W, int wstride, int c0, int lane,
    floatx4 (&acc)[4][2])
{
  const int lrow = lane & 15, quad = lane >> 4;
  const floatx4 fz = {0.f, 0.f, 0.f, 0.f};
  #pragma unroll
  for (int pt = 0; pt < 4; pt++) { acc[pt][0] = fz; acc[pt][1] = fz; }

  bf16x8 wf0 = *(const bf16x8*)(W + (size_t)(c0 + lrow) * wstride + quad * 8);
  bf16x8 wf1 = *(const bf16x8*)(W + (size_t)(c0 + 16 + lrow) * wstride + quad * 8);
  bf16x8 xf[4];
  #pragma unroll
  for (int pt = 0; pt < 4; pt++) {
    const int row = pt * 16 + lrow;
    xf[pt] = *(const bf16x8*)((const char*)X + row * 256
                              + ((quad * 16) ^ ((row & 7) << 4)));
  }

  #pragma unroll
  for (int ks = 0; ks < KSTEPS; ks++) {
    bf16x8 wn0, wn1, xn[4];
    if (ks + 1 < KSTEPS) {
      const int kn = (ks + 1) * 32 + quad * 8;
      wn0 = *(const bf16x8*)(W + (size_t)(c0 + lrow) * wstride + kn);
      wn1 = *(const bf16x8*)(W + (size_t)(c0 + 16 + lrow) * wstride + kn);
      #pragma unroll
      for (int pt = 0; pt < 4; pt++) {
        const int row = pt * 16 + lrow;
        xn[pt] = *(const bf16x8*)((const char*)X + row * 256
                                  + (((ks + 1) * 64 + quad * 16) ^ ((row & 7) << 4)));
      }
    }
    #pragma unroll
    for (int pt = 0; pt < 4; pt++) {
      acc[pt][0] = __builtin_amdgcn_mfma_f32_16x16x32_bf16(wf0, xf[pt], acc[pt][0], 0, 0, 0);
      acc[pt][1] = __builtin_amdgcn_mfma_f32_16x16x32_bf16(wf1, xf[pt], acc[pt][1], 0, 0, 0);
    }
    if (ks + 1 < KSTEPS) {
      wf0 = wn0; wf1 = wn1;
      #pragma unroll
      for (int pt = 0; pt < 4; pt++) xf[pt] = xn[pt];
    }
  }
}

// ---------------------------------------------------------------------------
// MLP1 (byte-identical to R6's measured-105.5 version).
// ---------------------------------------------------------------------------
__global__ __launch_bounds__(256, 4) void mlp1_kernel(
    const float* __restrict__ pos1, const float* __restrict__ pos2,
    const int* __restrict__ idx, const __bf16* __restrict__ f2t,
    const __bf16* __restrict__ w0p, const float* __restrict__ s10, const float* __restrict__ b10,
    const __bf16* __restrict__ w11b, const float* __restrict__ s11, const float* __restrict__ b11,
    const __bf16* __restrict__ w12b, const float* __restrict__ s12, const float* __restrict__ b12,
    __bf16* __restrict__ maxed)
{
  __shared__ __align__(16) __bf16 Xs[64 * 256];   // 32768 B exactly
  __bf16* const Y1 = Xs;                          // lower 16KB (post-L0)
  __bf16* const Y0 = Xs + 32 * 256;               // upper 16KB (post-bar2)
  __bf16* const Mst = Xs + 32 * 256;              // 8 x 264 bf16 (post-bar4)

  const int b = blockIdx.y;
  const int n0 = blockIdx.x * 8;
  const int tid = threadIdx.x;
  const int wave = tid >> 6, lane = tid & 63;
  const int lrow = lane & 15, quad = lane >> 4;
  const int c0 = 32 * wave;
  const int idxbase = (b * N_ + n0) * K_;

  {
    const int r0 = wave * 16;
    const int hf = lane >> 5;
    const int ch = lane & 31;
    int mr[8];
    #pragma unroll
    for (int i = 0; i < 8; i++)
      mr[i] = idx[idxbase + r0 + 2 * i + hf];
    #pragma unroll
    for (int i = 0; i < 8; i++) {
      const int r = r0 + 2 * i + hf;
      const char* src = (const char*)f2t
          + (((size_t)(b * M_ + mr[i])) << 9)
          + ((ch << 4) ^ ((r & 7) << 4));
      __builtin_amdgcn_global_load_lds(
          (const AS1G unsigned int*)src,
          (AS3L unsigned int*)(Xs + (r0 + 2 * i) * 256),
          16, 0, 0);
    }
  }

  bf16x8 xlast[4];
  #pragma unroll
  for (int pt = 0; pt < 4; pt++) { bf16x8 v = {}; xlast[pt] = v; }
  if (quad == 0) {
    #pragma unroll
    for (int pt = 0; pt < 4; pt++) {
      const int r = pt * 16 + lrow;
      const int m = idx[idxbase + r];
      const int n = n0 + (r >> 3);
      bf16x8 v = {};
      v[0] = (__bf16)(pos2[b * 3 * M_ + m]          - pos1[b * 3 * N_ + n]);
      v[1] = (__bf16)(pos2[b * 3 * M_ + M_ + m]     - pos1[b * 3 * N_ + N_ + n]);
      v[2] = (__bf16)(pos2[b * 3 * M_ + 2 * M_ + m] - pos1[b * 3 * N_ + 2 * N_ + n]);
      xlast[pt] = v;
    }
  }

  bf16x8 wf0 = *(const bf16x8*)(w0p + (size_t)(c0 + lrow) * 288 + quad * 8);
  bf16x8 wf1 = *(const bf16x8*)(w0p + (size_t)(c0 + 16 + lrow) * 288 + quad * 8);

  __syncthreads();                 // (1) all DMAs complete

  floatx4 acc[4][2];
  {
    const floatx4 fz = {0.f, 0.f, 0.f, 0.f};
    #pragma unroll
    for (int pt = 0; pt < 4; pt++) { acc[pt][0] = fz; acc[pt][1] = fz; }

    const int swz = (lrow & 7) << 4;
    bf16x8 xf[4];
    #pragma unroll
    for (int pt = 0; pt < 4; pt++)
      xf[pt] = *(const bf16x8*)((const char*)Xs + (pt * 16 + lrow) * 512
                                + ((quad * 16) ^ swz));

    #pragma unroll
    for (int ks = 0; ks < 9; ks++) {
      bf16x8 wn0, wn1, xn[4];
      if (ks < 8) {
        const int kn = (ks + 1) * 32 + quad * 8;
        wn0 = *(const bf16x8*)(w0p + (size_t)(c0 + lrow) * 288 + kn);
        wn1 = *(const bf16x8*)(w0p + (size_t)(c0 + 16 + lrow) * 288 + kn);
        if (ks < 7) {
          const int kb = ((ks + 1) * 64 + quad * 16) ^ swz;
          #pragma unroll
          for (int pt = 0; pt < 4; pt++)
            xn[pt] = *(const bf16x8*)((const char*)Xs + (pt * 16 + lrow) * 512 + kb);
        } else {
          #pragma unroll
          for (int pt = 0; pt < 4; pt++) xn[pt] = xlast[pt];
        }
      }
      #pragma unroll
      for (int pt = 0; pt < 4; pt++) {
        acc[pt][0] = __builtin_amdgcn_mfma_f32_16x16x32_bf16(wf0, xf[pt], acc[pt][0], 0, 0, 0);
        acc[pt][1] = __builtin_amdgcn_mfma_f32_16x16x32_bf16(wf1, xf[pt], acc[pt][1], 0, 0, 0);
      }
      if (ks < 8) {
        wf0 = wn0; wf1 = wn1;
        #pragma unroll
        for (int pt = 0; pt < 4; pt++) xf[pt] = xn[pt];
      }
    }
  }

  __syncthreads();                 // (2) upper Xs free

  #pragma unroll
  for (int pt = 0; pt < 4; pt++) {
    #pragma unroll
    for (int wt = 0; wt < 2; wt++) {
      const int colg = c0 + wt * 16 + quad * 4;
      floatx4 s4 = *(const floatx4*)(s10 + colg);
      floatx4 b4 = *(const floatx4*)(b10 + colg);
      bf16x4 pk;
      #pragma unroll
      for (int r = 0; r < 4; r++) {
        float v = acc[pt][wt][r] * s4[r] + b4[r];
        pk[r] = (__bf16)(v > 0.f ? v : 0.f);
      }
      const int row = pt * 16 + lrow;
      const int cb = colg * 2;
      *(bf16x4*)((char*)Y0 + row * 256
                 + ((cb & ~15) ^ ((row & 7) << 4)) + (cb & 15)) = pk;
    }
  }
  __syncthreads();                 // (3) Y0 ready

  {
    floatx4 a1c[4][2];
    mfma_kloop_swz<4>(Y0, w11b, 128, c0, lane, a1c);
    #pragma unroll
    for (int pt = 0; pt < 4; pt++) {
      #pragma unroll
      for (int wt = 0; wt < 2; wt++) {
        const int colg = c0 + wt * 16 + quad * 4;
        floatx4 s4 = *(const floatx4*)(s11 + colg);
        floatx4 b4 = *(const floatx4*)(b11 + colg);
        bf16x4 pk;
        #pragma unroll
        for (int r = 0; r < 4; r++) {
          float v = a1c[pt][wt][r] * s4[r] + b4[r];
          pk[r] = (__bf16)(v > 0.f ? v : 0.f);
        }
        const int row = pt * 16 + lrow;
        const int cb = colg * 2;
        *(bf16x4*)((char*)Y1 + row * 256
                   + ((cb & ~15) ^ ((row & 7) << 4)) + (cb & 15)) = pk;
      }
    }
  }
  __syncthreads();                 // (4) Y1 ready

  #pragma unroll
  for (int p = 0; p < 2; p++) {
    floatx4 a2c[4][2];
    mfma_kloop_swz<4>(Y1, w12b, 128, 128 * p + c0, lane, a2c);
    #pragma unroll
    for (int pt = 0; pt < 4; pt++) {
      #pragma unroll
      for (int wt = 0; wt < 2; wt++) {
        const int colg = 128 * p + c0 + wt * 16 + quad * 4;
        floatx4 s4 = *(const floatx4*)(s12 + colg);
        floatx4 b4 = *(const floatx4*)(b12 + colg);
        floatx4 v;
        #pragma unroll
        for (int r = 0; r < 4; r++) {
          float t = a2c[pt][wt][r] * s4[r] + b4[r];
          v[r] = t > 0.f ? t : 0.f;
        }
        #pragma unroll
        for (int st = 1; st <= 4; st <<= 1) {
          #pragma unroll
          for (int r = 0; r < 4; r++)
            v[r] = fmaxf(v[r], __shfl_xor(v[r], st, 64));
        }
        if ((lrow & 7) == 0) {
          const int point = pt * 2 + (lrow >> 3);
          bf16x4 pk;
          #pragma unroll
          for (int r = 0; r < 4; r++) pk[r] = (__bf16)v[r];
          *(bf16x4*)(Mst + point * 264 + colg) = pk;
        }
      }
    }
  }
  __syncthreads();                 // (5) Mst complete

  {
    const int point = tid >> 5, ch = tid & 31;
    bf16x8 v = *(const bf16x8*)(Mst + point * 264 + ch * 8);
    *(bf16x8*)(maxed + ((size_t)(b * N_ + n0 + point)) * 256 + ch * 8) = v;
  }
}

// ---------------------------------------------------------------------------
// MLP2 v3: LDS-staged A-panel. Block = 32 rows x ALL 256 out-cols, grid 1024.
// A = [maxed(256) | f1t(256)] bf16 staged ONCE into LDS (32 KB) via
// global_load_lds (linear dest, source-chunk XOR swizzle -- mlp1-proven),
// removing the old 8x redundant A reads (4 waves x 2 col-blocks) and the
// 8-scalar-gather f1 path. One barrier, then dense k-loop: 8 MFMA/kstep,
// W (4 frags) + A (2 frags) next-kstep register prefetch. K-accumulation
// order identical to v2 (ks 0..15) -> same numerics.
// ---------------------------------------------------------------------------
__global__ __launch_bounds__(256, 3) void mlp2_kernel(
    const __bf16* __restrict__ maxed, const __bf16* __restrict__ f1t,
    const __bf16* __restrict__ w20b, const float* __restrict__ s20,
    const float* __restrict__ b20, float* __restrict__ out)
{
  __shared__ __align__(16) __bf16 As[2][32 * 256];   // 32 KB total
  const int rows0 = blockIdx.x * 32;                 // global row = b*N + n
  const int b = rows0 >> 13;
  const int nbase = rows0 & (N_ - 1);
  const int tid = threadIdx.x;
  const int wave = tid >> 6, lane = tid & 63;
  const int lrow = lane & 15, quad = lane >> 4;
  const int c0 = 64 * wave;                          // wave's 64 out-cols

  // ---- stage: wave w rows [8w,8w+8), both k-halves; 2 rows per instr
  // (lanes 0-31 row r, 32-63 row r+1; 1KB linear dest); src chunk ^ (r&7).
  {
    const int r0 = wave * 8;
    const int hf = lane >> 5, ch = lane & 31;
    #pragma unroll
    for (int i = 0; i < 4; i++) {
      const int r = r0 + 2 * i + hf;
      const size_t srow = ((size_t)(rows0 + r)) << 9;     // 512B rows
      const int so = (ch << 4) ^ ((r & 7) << 4);
      __builtin_amdgcn_global_load_lds(
          (const AS1G unsigned int*)((const char*)maxed + srow + so),
          (AS3L unsigned int*)(&As[0][(r0 + 2 * i) * 256]), 16, 0, 0);
      __builtin_amdgcn_global_load_lds(
          (const AS1G unsigned int*)((const char*)f1t + srow + so),
          (AS3L unsigned int*)(&As[1][(r0 + 2 * i) * 256]), 16, 0, 0);
    }
  }

  // W kstep-0 fragments issued before the barrier (L2-hot)
  bf16x8 wf[4];
  #pragma unroll
  for (int wt = 0; wt < 4; wt++)
    wf[wt] = *(const bf16x8*)(w20b + (size_t)(c0 + wt * 16 + lrow) * 512 + quad * 8);

  __syncthreads();                 // staging DMAs complete

  floatx4 acc[2][4];
  const floatx4 fz = {0.f, 0.f, 0.f, 0.f};
  #pragma unroll
  for (int mt = 0; mt < 2; mt++)
    #pragma unroll
    for (int wt = 0; wt < 4; wt++) acc[mt][wt] = fz;

  auto aaddr = [&](int ks, int mt) -> const char* {
    const int row = mt * 16 + lrow;
    return (const char*)(&As[ks >> 3][0]) + row * 512
           + ((((ks & 7) * 64) + quad * 16) ^ ((row & 7) << 4));
  };

  bf16x8 af[2];
  af[0] = *(const bf16x8*)aaddr(0, 0);
  af[1] = *(const bf16x8*)aaddr(0, 1);

  #pragma unroll
  for (int ks = 0; ks < 16; ks++) {
    bf16x8 wn[4], an[2];
    if (ks < 15) {
      const int kn = (ks + 1) * 32 + quad * 8;
      #pragma unroll
      for (int wt = 0; wt < 4; wt++)
        wn[wt] = *(const bf16x8*)(w20b + (size_t)(c0 + wt * 16 + lrow) * 512 + kn);
      an[0] = *(const bf16x8*)aaddr(ks + 1, 0);
      an[1] = *(const bf16x8*)aaddr(ks + 1, 1);
    }
    #pragma unroll
    for (int mt = 0; mt < 2; mt++)
      #pragma unroll
      for (int wt = 0; wt < 4; wt++)
        acc[mt][wt] = __builtin_amdgcn_mfma_f32_16x16x32_bf16(af[mt], wf[wt], acc[mt][wt], 0, 0, 0);
    if (ks < 15) {
      #pragma unroll
      for (int wt = 0; wt < 4; wt++) wf[wt] = wn[wt];
      af[0] = an[0]; af[1] = an[1];
    }
  }

  // epilogue: D[row=quad*4+r (n-offset)][col=lrow (out-ch)] per frag
  #pragma unroll
  for (int wt = 0; wt < 4; wt++) {
    const int col = c0 + wt * 16 + lrow;
    const float s = s20[col];
    const float bb = b20[col];
    #pragma unroll
    for (int mt = 0; mt < 2; mt++) {
      floatx4 pk;
      #pragma unroll
      for (int r = 0; r < 4; r++) {
        float v = acc[mt][wt][r] * s + bb;
        pk[r] = v > 0.f ? v : 0.f;
      }
      const int n = nbase + mt * 16 + quad * 4;
      *(floatx4*)(out + ((size_t)(b * 256 + col)) * N_ + n) = pk;
    }
  }
}

// ---------------------------------------------------------------------------
extern "C" void kernel_launch(void* const* d_in, const int* in_sizes, int n_in,
                              void* d_out, int out_size, void* d_ws, size_t ws_size,
                              hipStream_t stream)
{
  const float* pos1     = (const float*)d_in[0];
  const float* pos2     = (const float*)d_in[1];
  const float* feature1 = (const float*)d_in[2];
  const float* feature2 = (const float*)d_in[3];
  const float* w1_0 = (const float*)d_in[4];
  const float* s1_0 = (const float*)d_in[5];
  const float* b1_0 = (const float*)d_in[6];
  const float* w1_1 = (const float*)d_in[7];
  const float* s1_1 = (const float*)d_in[8];
  const float* b1_1 = (const float*)d_in[9];
  const float* w1_2 = (const float*)d_in[10];
  const float* s1_2 = (const float*)d_in[11];
  const float* b1_2 = (const float*)d_in[12];
  const float* w2_0 = (const float*)d_in[13];
  const float* s2_0 = (const float*)d_in[14];
  const float* b2_0 = (const float*)d_in[15];

  // Workspace layout (39,231,488 B total)
  char* ws = (char*)d_ws;
  int*    idx   = (int*)(ws);                    //  1,048,576 @ 0
  __bf16* f2t   = (__bf16*)(ws + 1048576);       //  4,194,304
  __bf16* f1t   = (__bf16*)(ws + 5242880);       // 16,777,216
  __bf16* maxed = (__bf16*)(ws + 22020096);      // 16,777,216
  __bf16* w0p   = (__bf16*)(ws + 38797312);      //     73,728
  __bf16* w11b  = (__bf16*)(ws + 38871040);      //     32,768
  __bf16* w12b  = (__bf16*)(ws + 38903808);      //     65,536
  __bf16* w20b  = (__bf16*)(ws + 38969344);      //    262,144
  // part (4 MB) aliases maxed: written by pre_knn, read by knn_merge,
  // clobbered only later by mlp1 (stream-ordered).
  u64k*   part  = (u64k*)(ws + 22020096);

  pre_knn<<<dim3(12112), 256, 0, stream>>>(
      w1_0, w1_1, w1_2, w2_0, feature1, feature2, pos1, pos2,
      w0p, w11b, w12b, w20b, f2t, f1t, part);
  knn_merge<<<dim3(N_ * B_ / 256), 256, 0, stream>>>(part, idx);
  mlp1_kernel<<<dim3(N_ / 8, B_), 256, 0, stream>>>(
      pos1, pos2, idx, f2t, w0p, s1_0, b1_0, w11b, s1_1, b1_1, w12b, s1_2, b1_2, maxed);
  mlp2_kernel<<<dim3(N_ * B_ / 32), 256, 0, stream>>>(maxed, f1t, w20b, s2_0, b2_0,
                                                      (float*)d_out);
}